// Round 4
// baseline (250.264 us; speedup 1.0000x reference)
//
#include <hip/hip_runtime.h>
#include <stdint.h>

// ---------------- problem constants ----------------
#define HW_      102400          // 320*320
#define C_       256
#define N_       1024
#define P_       2               // pairs
#define CHUNKS_  64              // HW chunks per (pair, n-block)
#define CHUNK_PX 1600            // 5 rows of 320 -> chunks row-aligned
#define ITERS_   25              // 25 * 64 px = 1600 px per chunk
#define NB_      4               // n-blocks of 256 keypoints
#define K2_      144.269504088896340f   // 100 / ln(2)
#define MOFF_    (-72.134752044448170f) // -K2_ * 0.5  (fixed softmax max = 0.5 in cosine space)

typedef __attribute__((ext_vector_type(8))) short bf16x8;
typedef __attribute__((ext_vector_type(4))) float f32x4;
typedef __attribute__((ext_vector_type(4))) uint32_t u32x4;

// ws layout (bytes):
//   tgt bf16: [0, 1048576)       2*1024*256 bf16, [p][n][c]
//   partials: [1048576, +4MB)    2*64*2*1024 float4 (S,U,V,-)
#define WS_TGT_OFF  0
#define WS_PAR_OFF  1048576

__device__ __forceinline__ uint32_t packbf(float a, float b) {
  uint32_t r;
  asm("v_cvt_pk_bf16_f32 %0, %1, %2" : "=v"(r) : "v"(a), "v"(b));
  return r;
}
__device__ __forceinline__ float fexp2(float x) {
  return __builtin_amdgcn_exp2f(x);
}

// ---------------- kernel 1: normalize tgt keypoint descs -> bf16 [p][n][c]; copy weights ----------------
__global__ __launch_bounds__(256)
void k_pre(const float* __restrict__ kdesc, const float* __restrict__ kscores,
           uint16_t* __restrict__ tgt, float* __restrict__ out) {
  const int t = blockIdx.x * 256 + threadIdx.x;   // 0..2047
  const int p = t >> 10, n = t & 1023;
  const float* src = kdesc + (size_t)(p * 2 + 1) * C_ * N_ + n;   // tgt ids 1,3
  float s = 0.f;
  #pragma unroll 16
  for (int c = 0; c < C_; ++c) { const float v = src[c * N_]; s = fmaf(v, v, s); }
  const float inv = 1.f / fmaxf(sqrtf(s), 1e-12f);
  uint32_t* dst = (uint32_t*)(tgt + (size_t)t * C_);
  #pragma unroll 4
  for (int c8 = 0; c8 < C_; c8 += 8) {
    uint4 wv;
    wv.x = packbf(src[(c8 + 0) * N_] * inv, src[(c8 + 1) * N_] * inv);
    wv.y = packbf(src[(c8 + 2) * N_] * inv, src[(c8 + 3) * N_] * inv);
    wv.z = packbf(src[(c8 + 4) * N_] * inv, src[(c8 + 5) * N_] * inv);
    wv.w = packbf(src[(c8 + 6) * N_] * inv, src[(c8 + 7) * N_] * inv);
    *(uint4*)&dst[c8 / 2] = wv;
  }
  out[4096 + t] = kscores[(p * 2 + 1) * N_ + n];   // match_weights
}

// ---------------- kernel 2: fused norm + QK^T + fixed-max softmax + soft-argmax ----------------
// Stages RAW src as bf16 (1 barrier/iter, double-buffered). Per-pixel inv-norms are computed
// IN-REGISTER from the A-fragments during the MFMA phase (each wave's a0/a1 span all 256
// channels of its pixel rows across the 4 g4 groups): sumsq-unpack + 2 shfl_xor + 8 bpermute.
// The 4 blocks sharing a (p,chunk) tile map to the SAME XCD (bids differ by 8 under
// round-robin) so readers 2-4 hit L2/L3 -> dense read from HBM ~once (verified: FETCH 109MB).
__global__ __launch_bounds__(512, 2)
void k_main(const float* __restrict__ dense, const uint16_t* __restrict__ tgt,
            float4* __restrict__ partials) {
  __shared__ uint32_t lds[2 * 64 * 128];   // 2 bufs x (64 px x 256 bf16), XOR-swizzled; 64KB

  // ---- XCD co-locating decode: same (p,chunk) -> bids {x, x+8, x+16, x+24} ----
  const int bid   = blockIdx.x;            // 0..511
  const int xcd   = bid & 7;
  const int rr    = bid >> 3;              // 0..63
  const int grp   = xcd + 8 * (rr >> 2);   // 0..127 = (p,chunk)
  const int nb    = rr & 3;
  const int p     = grp >> 6;
  const int chunk = grp & 63;

  const int t    = threadIdx.x;
  const int lane = t & 63;
  const int w    = t >> 6;
  const int l15  = lane & 15;
  const int g4   = lane >> 4;
  const int h    = w & 1;    // m-half: 32 px
  const int q    = w >> 1;   // n-quarter: 64 keypoints

  const float* plane = dense + (size_t)(p * 2) * C_ * HW_;   // src ids 0,2

  // ---- B fragments (tgt, [n][c] bf16): lane n = l15, k-slice c = k*32 + g4*8 .. +7 ----
  bf16x8 Bf[4][8];
  const int nbase = nb * 256 + q * 64;
  #pragma unroll
  for (int j = 0; j < 4; ++j) {
    const uint16_t* tp = tgt + (size_t)(p * N_ + nbase + j * 16 + l15) * C_ + g4 * 8;
    #pragma unroll
    for (int k = 0; k < 8; ++k) Bf[j][k] = *(const bf16x8*)(tp + k * 32);
  }

  float stS[4], stU[4], stV[4];
  #pragma unroll
  for (int j = 0; j < 4; ++j) { stS[j] = 0.f; stU[j] = 0.f; stV[j] = 0.f; }

  // staging: thread t loads 8 channel rows (c8..c8+7) x 4 px (mi..mi+3), raw f32
  const int mi   = (t & 15) * 4;
  const int c8   = (t >> 4) * 8;
  const int wcol = (t >> 4) * 4;           // dword col within LDS row
  const int px0  = chunk * CHUNK_PX;

  const int row0  = h * 32 + l15;          // A-frag row (subtile 1 = +16)
  const int row1  = row0 + 16;
  const int sw0   = ((row0 ^ (row0 >> 3)) & 7) << 2;   // phase-uniform read swizzle
  const int sw1   = ((row1 ^ (row1 >> 3)) & 7) << 2;
  const int base0 = row0 * 128;
  const int base1 = row1 * 128;
  const int lr0   = h * 32 + g4 * 4;       // this lane's acc row base (s=0)

  uint32_t* bufR = lds;
  uint32_t* bufW = lds + 64 * 128;

  float fva[8][4];

  // ---- prologue: load tile 0, pack raw bf16 -> bufR ----
  {
    const int px = px0 + mi;
    #pragma unroll
    for (int j = 0; j < 8; ++j) {
      float4 v = *(const float4*)(plane + (size_t)(c8 + j) * HW_ + px);
      fva[j][0] = v.x; fva[j][1] = v.y; fva[j][2] = v.z; fva[j][3] = v.w;
    }
    #pragma unroll
    for (int i = 0; i < 4; ++i) {
      const int row = mi + i;
      const int sw  = ((row ^ (row >> 3)) & 7) << 2;
      uint4 wv;
      wv.x = packbf(fva[0][i], fva[1][i]);
      wv.y = packbf(fva[2][i], fva[3][i]);
      wv.z = packbf(fva[4][i], fva[5][i]);
      wv.w = packbf(fva[6][i], fva[7][i]);
      *(uint4*)&bufR[row * 128 + (wcol ^ sw)] = wv;
    }
  }
  __syncthreads();

  for (int iter = 0; iter < ITERS_; ++iter) {
    const bool more = (iter + 1 < ITERS_);

    // ---- issue next tile's global loads (latency hides under MFMA+softmax) ----
    if (more) {
      const int px = px0 + (iter + 1) * 64 + mi;
      #pragma unroll
      for (int j = 0; j < 8; ++j) {
        float4 v = *(const float4*)(plane + (size_t)(c8 + j) * HW_ + px);
        fva[j][0] = v.x; fva[j][1] = v.y; fva[j][2] = v.z; fva[j][3] = v.w;
      }
    }

    // ---- MFMA from bufR + in-register sumsq of the A rows ----
    f32x4 acc[4][2];
    #pragma unroll
    for (int j = 0; j < 4; ++j) {
      acc[j][0] = (f32x4){0.f, 0.f, 0.f, 0.f};
      acc[j][1] = (f32x4){0.f, 0.f, 0.f, 0.f};
    }
    float p0a = 0.f, p0b = 0.f, p1a = 0.f, p1b = 0.f;   // 2 accums/row vs dep chain
    #pragma unroll
    for (int k = 0; k < 8; ++k) {
      const int col = k * 16 + g4 * 4;
      bf16x8 a0 = *(const bf16x8*)&bufR[base0 + (col ^ sw0)];
      bf16x8 a1 = *(const bf16x8*)&bufR[base1 + (col ^ sw1)];
      #pragma unroll
      for (int j = 0; j < 4; ++j) {
        acc[j][0] = __builtin_amdgcn_mfma_f32_16x16x32_bf16(a0, Bf[j][k], acc[j][0], 0, 0, 0);
        acc[j][1] = __builtin_amdgcn_mfma_f32_16x16x32_bf16(a1, Bf[j][k], acc[j][1], 0, 0, 0);
      }
      const u32x4 u0 = __builtin_bit_cast(u32x4, a0);
      const u32x4 u1 = __builtin_bit_cast(u32x4, a1);
      #pragma unroll
      for (int d = 0; d < 4; ++d) {
        const float l0 = __builtin_bit_cast(float, u0[d] << 16);
        const float h0 = __builtin_bit_cast(float, u0[d] & 0xFFFF0000u);
        const float l1 = __builtin_bit_cast(float, u1[d] << 16);
        const float h1 = __builtin_bit_cast(float, u1[d] & 0xFFFF0000u);
        p0a = fmaf(l0, l0, p0a); p0b = fmaf(h0, h0, p0b);
        p1a = fmaf(l1, l1, p1a); p1b = fmaf(h1, h1, p1b);
      }
    }

    // ---- in-wave norm reduce: lanes sharing l15 hold disjoint channel quarters ----
    float ps0 = p0a + p0b, ps1 = p1a + p1b;
    ps0 += __shfl_xor(ps0, 16, 64); ps0 += __shfl_xor(ps0, 32, 64);
    ps1 += __shfl_xor(ps1, 16, 64); ps1 += __shfl_xor(ps1, 32, 64);
    const float inv0 = 1.f / fmaxf(sqrtf(ps0), 1e-12f);   // norm of row h*32+l15
    const float inv1 = 1.f / fmaxf(sqrtf(ps1), 1e-12f);   // norm of row h*32+16+l15
    // redistribute to acc-row owners: row lr0+e lives at source lane l15 = g4*4+e
    float kv0[4], kv1[4];
    #pragma unroll
    for (int e = 0; e < 4; ++e) {
      kv0[e] = K2_ * __shfl(inv0, g4 * 4 + e, 64);
      kv1[e] = K2_ * __shfl(inv1, g4 * 4 + e, 64);
    }

    // ---- fixed-max softmax + soft-argmax accumulation ----
    const int rb = iter * 64 + lr0;
    #pragma unroll
    for (int s = 0; s < 2; ++s) {
      #pragma unroll
      for (int e = 0; e < 4; ++e) {
        const int r  = rb + s * 16 + e;            // < 1600
        const int vl = (r * 6554) >> 21;           // == r / 320
        const float vf = (float)(chunk * 5 + vl);
        const float uf = (float)(r - vl * 320);
        const float kve = s ? kv1[e] : kv0[e];
        #pragma unroll
        for (int j = 0; j < 4; ++j) {
          const float ev = fexp2(fmaf(kve, acc[j][s][e], MOFF_));
          stS[j] += ev;
          stU[j] = fmaf(ev, uf, stU[j]);
          stV[j] = fmaf(ev, vf, stV[j]);
        }
      }
    }

    // ---- pack + write next tile into bufW (compiler inserts vmcnt wait) ----
    if (more) {
      #pragma unroll
      for (int i = 0; i < 4; ++i) {
        const int row = mi + i;
        const int sw  = ((row ^ (row >> 3)) & 7) << 2;
        uint4 wv;
        wv.x = packbf(fva[0][i], fva[1][i]);
        wv.y = packbf(fva[2][i], fva[3][i]);
        wv.z = packbf(fva[4][i], fva[5][i]);
        wv.w = packbf(fva[6][i], fva[7][i]);
        *(uint4*)&bufW[row * 128 + (wcol ^ sw)] = wv;
      }
    }
    __syncthreads();
    uint32_t* tmp = bufR; bufR = bufW; bufW = tmp;
  }

  // ---- merge the 4 lane-groups (disjoint px subsets, same n) ----
  #pragma unroll
  for (int j = 0; j < 4; ++j) {
    float S = stS[j], U = stU[j], V = stV[j];
    S += __shfl_xor(S, 16, 64); U += __shfl_xor(U, 16, 64); V += __shfl_xor(V, 16, 64);
    S += __shfl_xor(S, 32, 64); U += __shfl_xor(U, 32, 64); V += __shfl_xor(V, 32, 64);
    if (lane < 16) {
      const int n = nbase + j * 16 + l15;
      partials[((size_t)(p * CHUNKS_ + chunk) * 2 + h) * N_ + n] = make_float4(S, U, V, 0.f);
    }
  }
}

// ---------------- kernel 3: sum 128 partials per (p, n) -> coords; ids ----------------
__global__ void k_final(const float4* __restrict__ partials, float* __restrict__ out) {
  const int t = blockIdx.x * blockDim.x + threadIdx.x;   // 0..2047
  const int p = t >> 10, n = t & 1023;
  float S = 0.f, U = 0.f, V = 0.f;
  #pragma unroll 4
  for (int s = 0; s < 2 * CHUNKS_; ++s) {
    const float4 v = partials[((size_t)p * 2 * CHUNKS_ + s) * N_ + n];
    S += v.x; U += v.y; V += v.z;
  }
  out[(size_t)(p * N_ + n) * 2 + 0] = U / S;
  out[(size_t)(p * N_ + n) * 2 + 1] = V / S;
  if (t < 4) {
    const float ids[4] = {1.f, 3.f, 0.f, 2.f};  // tgt_ids then src_ids
    out[6144 + t] = ids[t];
  }
}

// ---------------- host launch ----------------
extern "C" void kernel_launch(void* const* d_in, const int* in_sizes, int n_in,
                              void* d_out, int out_size, void* d_ws, size_t ws_size,
                              hipStream_t stream) {
  const float* kscores = (const float*)d_in[0];   // (4,1,1024)
  const float* kdesc   = (const float*)d_in[1];   // (4,256,1024)
  const float* dense   = (const float*)d_in[2];   // (4,256,320,320)
  float* out = (float*)d_out;

  char* ws = (char*)d_ws;
  uint16_t* tgt = (uint16_t*)(ws + WS_TGT_OFF);
  float4*   par = (float4*)(ws + WS_PAR_OFF);

  k_pre<<<(P_ * N_) / 256, 256, 0, stream>>>(kdesc, kscores, tgt, out);
  k_main<<<P_ * NB_ * CHUNKS_, 512, 0, stream>>>(dense, tgt, par);
  k_final<<<(P_ * N_) / 256, 256, 0, stream>>>(par, out);
}

// Round 5
// 219.808 us; speedup vs baseline: 1.1386x; 1.1386x over previous
//
#include <hip/hip_runtime.h>
#include <stdint.h>

// ---------------- problem constants ----------------
#define HW_      102400          // 320*320
#define C_       256
#define N_       1024
#define P_       2               // pairs
#define TILES_   1600            // 64-px tiles per src plane
#define CHUNKS_  64              // chunks per (pair, n-block)
#define CHUNK_PX 1600            // 25 tiles of 64 px
#define ITERS_   25
#define NB_      8               // n-blocks of 128 keypoints
#define K2_      144.269504088896340f   // 100 / ln(2)
#define MOFF_    (-72.134752044448170f) // -K2_ * 0.5 (fixed softmax max, cosine logits <= ~1.02)

typedef __attribute__((ext_vector_type(8))) short bf16x8;
typedef __attribute__((ext_vector_type(4))) float f32x4;

// ws layout (bytes):
//   tgt bf16 : [0, 1048576)        2*1024*256 bf16, [p][n][c]
//   partials : [1048576, 5242880)  2*64*2*1024 float4 (S,U,V,-)
//   PN       : [5242880, +100MB)   normalized src as bf16, [p][tile][r][dphys] dwords,
//              dphys = dlog ^ SW(r); dword = channels (2*dlog, 2*dlog+1), low = even ch
#define WS_TGT_OFF  0
#define WS_PAR_OFF  1048576
#define WS_PN_OFF   5242880

#define SWR(r) (((r) ^ ((r) >> 3)) & 7)   // swizzle (in 4-dword groups)

__device__ __forceinline__ uint32_t packbf(float a, float b) {
  uint32_t r;
  asm("v_cvt_pk_bf16_f32 %0, %1, %2" : "=v"(r) : "v"(a), "v"(b));
  return r;
}
__device__ __forceinline__ float fexp2(float x) {
  return __builtin_amdgcn_exp2f(x);
}
__device__ __forceinline__ void dma16(const uint32_t* g, uint32_t* l) {
  // async global->LDS, 16B per lane; LDS dest = wave-uniform base + lane*16
  __builtin_amdgcn_global_load_lds(
      (const __attribute__((address_space(1))) uint32_t*)g,
      (__attribute__((address_space(3))) uint32_t*)l, 16, 0, 0);
}

// ---------------- kernel 1: (a) prenorm dense -> PN (bf16, swizzled); (b) tgt normalize ----------------
__global__ __launch_bounds__(256)
void k_pre(const float* __restrict__ dense, const float* __restrict__ kdesc,
           const float* __restrict__ kscores, uint32_t* __restrict__ PN,
           uint16_t* __restrict__ tgt, float* __restrict__ out) {
  const int bid = blockIdx.x;
  if (bid < P_ * TILES_) {
    // ---- prenorm: block = one 64-px tile; wave cq owns channels cq*64..+63, lane = px row r ----
    const int p = bid / TILES_, tile = bid % TILES_;
    const int r  = threadIdx.x & 63;
    const int cq = threadIdx.x >> 6;
    const float* src = dense + (size_t)(p * 2) * C_ * HW_ + (size_t)(cq * 64) * HW_
                     + tile * 64 + r;                       // src ids 0,2
    float v[64];
    #pragma unroll
    for (int c = 0; c < 64; ++c) v[c] = src[(size_t)c * HW_];
    float s0 = 0.f, s1 = 0.f, s2 = 0.f, s3 = 0.f;
    #pragma unroll
    for (int c = 0; c < 64; c += 4) {
      s0 = fmaf(v[c + 0], v[c + 0], s0);
      s1 = fmaf(v[c + 1], v[c + 1], s1);
      s2 = fmaf(v[c + 2], v[c + 2], s2);
      s3 = fmaf(v[c + 3], v[c + 3], s3);
    }
    __shared__ float part[4][64];
    __shared__ float sinv[64];
    part[cq][r] = (s0 + s1) + (s2 + s3);
    __syncthreads();
    if (threadIdx.x < 64) {
      const float s = part[0][threadIdx.x] + part[1][threadIdx.x]
                    + part[2][threadIdx.x] + part[3][threadIdx.x];
      sinv[threadIdx.x] = 1.f / fmaxf(sqrtf(s), 1e-12f);
    }
    __syncthreads();
    const float inv = sinv[r];
    const int s8 = SWR(r);
    uint32_t* dst = PN + ((size_t)(p * TILES_ + tile) << 13) + r * 128 + cq * 32;
    // register-group rg (channels 8rg..+7, static indices) -> phys group rg^s8 (runtime addr)
    #pragma unroll
    for (int rg = 0; rg < 8; ++rg) {
      uint4 wv;
      wv.x = packbf(v[rg * 8 + 0] * inv, v[rg * 8 + 1] * inv);
      wv.y = packbf(v[rg * 8 + 2] * inv, v[rg * 8 + 3] * inv);
      wv.z = packbf(v[rg * 8 + 4] * inv, v[rg * 8 + 5] * inv);
      wv.w = packbf(v[rg * 8 + 6] * inv, v[rg * 8 + 7] * inv);
      *(uint4*)&dst[(rg ^ s8) << 2] = wv;
    }
  } else {
    // ---- tgt keypoint descriptors -> normalized bf16 [p][n][c]; copy weights ----
    const int t = (bid - P_ * TILES_) * 256 + threadIdx.x;   // 0..2047
    const int p = t >> 10, n = t & 1023;
    const float* src = kdesc + (size_t)(p * 2 + 1) * C_ * N_ + n;   // tgt ids 1,3
    float s = 0.f;
    #pragma unroll 16
    for (int c = 0; c < C_; ++c) { const float v = src[c * N_]; s = fmaf(v, v, s); }
    const float inv = 1.f / fmaxf(sqrtf(s), 1e-12f);
    uint32_t* dst = (uint32_t*)(tgt + (size_t)t * C_);
    #pragma unroll 4
    for (int c8 = 0; c8 < C_; c8 += 8) {
      uint4 wv;
      wv.x = packbf(src[(c8 + 0) * N_] * inv, src[(c8 + 1) * N_] * inv);
      wv.y = packbf(src[(c8 + 2) * N_] * inv, src[(c8 + 3) * N_] * inv);
      wv.z = packbf(src[(c8 + 4) * N_] * inv, src[(c8 + 5) * N_] * inv);
      wv.w = packbf(src[(c8 + 6) * N_] * inv, src[(c8 + 7) * N_] * inv);
      *(uint4*)&dst[c8 / 2] = wv;
    }
    out[4096 + t] = kscores[(p * 2 + 1) * N_ + n];   // match_weights
  }
}

// ---------------- kernel 2: DMA-staged QK^T + fixed-max softmax + soft-argmax ----------------
// block: 512 thr (8 waves = 2(h) x 4(q)); 128 keypoints x 1600 px chunk. grid 1024.
// Inner loop: 4 global_load_lds + 16 ds_read_b128 + 32 MFMA + 16 exp + 1 barrier. No staging VALU.
// The 8 blocks sharing a (p,chunk) map to the SAME XCD (bids = xcd mod 8, consecutive groups).
__global__ __launch_bounds__(512, 3)
void k_main(const uint32_t* __restrict__ PN, const uint16_t* __restrict__ tgt,
            float4* __restrict__ partials) {
  __shared__ uint32_t lds[2 * 64 * 128];   // 2 bufs x (64 px x 256 bf16) = 64 KB

  const int bid = blockIdx.x;              // 0..1023
  const int xcd = bid & 7;
  const int rr  = bid >> 3;                // 0..127
  const int nb  = rr & 7;
  const int grp = xcd + 8 * (rr >> 3);     // 0..127 = (p, chunk)
  const int p     = grp >> 6;
  const int chunk = grp & 63;

  const int t    = threadIdx.x;
  const int lane = t & 63;
  const int w    = t >> 6;
  const int l15  = lane & 15;
  const int g4   = lane >> 4;
  const int h    = w & 1;    // px half (32 rows)
  const int q    = w >> 1;   // n quarter (32 n)

  // ---- B fragments (tgt, [n][c] bf16): 2 j-tiles x 8 k-slices = 64 VGPR ----
  bf16x8 Bf[2][8];
  const int nbase = nb * 128 + q * 32;
  #pragma unroll
  for (int j = 0; j < 2; ++j) {
    const uint16_t* tp = tgt + (size_t)(p * N_ + nbase + j * 16 + l15) * C_ + g4 * 8;
    #pragma unroll
    for (int k = 0; k < 8; ++k) Bf[j][k] = *(const bf16x8*)(tp + k * 32);
  }

  float stS[2], stU[2], stV[2];
  #pragma unroll
  for (int j = 0; j < 2; ++j) { stS[j] = 0.f; stU[j] = 0.f; stV[j] = 0.f; }

  const int row0  = h * 32 + l15;
  const int row1  = row0 + 16;
  const int sw0   = SWR(row0) << 2;
  const int sw1   = SWR(row1) << 2;
  const int base0 = row0 * 128;
  const int base1 = row1 * 128;
  const int lr0   = h * 32 + g4 * 4;       // acc row base (s=0)

  // DMA: wave w stages 4KB of the 32KB tile; source is contiguous (pre-permuted by k_pre)
  const uint32_t* PNp = PN + ((size_t)(p * TILES_ + chunk * 25) << 13) + w * 1024 + lane * 4;

  // ---- prologue: stage tile 0 into buf 0 ----
  #pragma unroll
  for (int jj = 0; jj < 4; ++jj) dma16(PNp + jj * 256, &lds[w * 1024 + jj * 256]);
  __syncthreads();   // full vmcnt drain -> tile 0 resident

  int rbuf = 0;
  for (int iter = 0; iter < ITERS_; ++iter) {
    // ---- issue next tile's DMA into the other buffer (hides under MFMA+softmax) ----
    if (iter + 1 < ITERS_) {
      const uint32_t* s = PNp + ((size_t)(iter + 1) << 13);
      uint32_t* d = &lds[(rbuf ^ 1) * 8192 + w * 1024];
      #pragma unroll
      for (int jj = 0; jj < 4; ++jj) dma16(s + jj * 256, d + jj * 256);
    }

    // ---- MFMA from bufR ----
    const uint32_t* bufR = &lds[rbuf * 8192];
    f32x4 acc[2][2];
    #pragma unroll
    for (int j = 0; j < 2; ++j) {
      acc[j][0] = (f32x4){0.f, 0.f, 0.f, 0.f};
      acc[j][1] = (f32x4){0.f, 0.f, 0.f, 0.f};
    }
    #pragma unroll
    for (int k = 0; k < 8; ++k) {
      const int col = k * 16 + g4 * 4;
      bf16x8 a0 = *(const bf16x8*)&bufR[base0 + (col ^ sw0)];
      bf16x8 a1 = *(const bf16x8*)&bufR[base1 + (col ^ sw1)];
      acc[0][0] = __builtin_amdgcn_mfma_f32_16x16x32_bf16(a0, Bf[0][k], acc[0][0], 0, 0, 0);
      acc[0][1] = __builtin_amdgcn_mfma_f32_16x16x32_bf16(a1, Bf[0][k], acc[0][1], 0, 0, 0);
      acc[1][0] = __builtin_amdgcn_mfma_f32_16x16x32_bf16(a0, Bf[1][k], acc[1][0], 0, 0, 0);
      acc[1][1] = __builtin_amdgcn_mfma_f32_16x16x32_bf16(a1, Bf[1][k], acc[1][1], 0, 0, 0);
    }

    // ---- fixed-max softmax + soft-argmax ----
    const int rb = iter * 64 + lr0;
    #pragma unroll
    for (int s = 0; s < 2; ++s) {
      #pragma unroll
      for (int e = 0; e < 4; ++e) {
        const int r  = rb + s * 16 + e;            // < 1600
        const int vl = (r * 6554) >> 21;           // == r / 320
        const float vf = (float)(chunk * 5 + vl);
        const float uf = (float)(r - vl * 320);
        #pragma unroll
        for (int j = 0; j < 2; ++j) {
          const float ev = fexp2(fmaf(K2_, acc[j][s][e], MOFF_));
          stS[j] += ev;
          stU[j] = fmaf(ev, uf, stU[j]);
          stV[j] = fmaf(ev, vf, stV[j]);
        }
      }
    }

    __syncthreads();   // drains DMA (vmcnt) + publishes; swap
    rbuf ^= 1;
  }

  // ---- merge the 4 g4-groups (disjoint px subsets, same n) ----
  #pragma unroll
  for (int j = 0; j < 2; ++j) {
    float S = stS[j], U = stU[j], V = stV[j];
    S += __shfl_xor(S, 16, 64); U += __shfl_xor(U, 16, 64); V += __shfl_xor(V, 16, 64);
    S += __shfl_xor(S, 32, 64); U += __shfl_xor(U, 32, 64); V += __shfl_xor(V, 32, 64);
    if (lane < 16) {
      const int n = nbase + j * 16 + l15;
      partials[((size_t)(p * CHUNKS_ + chunk) * 2 + h) * N_ + n] = make_float4(S, U, V, 0.f);
    }
  }
}

// ---------------- kernel 3: sum 128 partials per (p, n) -> coords; ids ----------------
__global__ void k_final(const float4* __restrict__ partials, float* __restrict__ out) {
  const int t = blockIdx.x * blockDim.x + threadIdx.x;   // 0..2047
  const int p = t >> 10, n = t & 1023;
  float S = 0.f, U = 0.f, V = 0.f;
  #pragma unroll 4
  for (int s = 0; s < 2 * CHUNKS_; ++s) {
    const float4 v = partials[((size_t)p * 2 * CHUNKS_ + s) * N_ + n];
    S += v.x; U += v.y; V += v.z;
  }
  out[(size_t)(p * N_ + n) * 2 + 0] = U / S;
  out[(size_t)(p * N_ + n) * 2 + 1] = V / S;
  if (t < 4) {
    const float ids[4] = {1.f, 3.f, 0.f, 2.f};  // tgt_ids then src_ids
    out[6144 + t] = ids[t];
  }
}

// ---------------- host launch ----------------
extern "C" void kernel_launch(void* const* d_in, const int* in_sizes, int n_in,
                              void* d_out, int out_size, void* d_ws, size_t ws_size,
                              hipStream_t stream) {
  const float* kscores = (const float*)d_in[0];   // (4,1,1024)
  const float* kdesc   = (const float*)d_in[1];   // (4,256,1024)
  const float* dense   = (const float*)d_in[2];   // (4,256,320,320)
  float* out = (float*)d_out;

  char* ws = (char*)d_ws;
  uint16_t* tgt = (uint16_t*)(ws + WS_TGT_OFF);
  float4*   par = (float4*)(ws + WS_PAR_OFF);
  uint32_t* PN  = (uint32_t*)(ws + WS_PN_OFF);

  k_pre<<<P_ * TILES_ + (P_ * N_) / 256, 256, 0, stream>>>(dense, kdesc, kscores, PN, tgt, out);
  k_main<<<P_ * NB_ * CHUNKS_, 512, 0, stream>>>(PN, tgt, par);
  k_final<<<(P_ * N_) / 256, 256, 0, stream>>>(par, out);
}